// Round 1
// baseline (307.400 us; speedup 1.0000x reference)
//
#include <hip/hip_runtime.h>
#include <hip/hip_bf16.h>
#include <math.h>

#define T_DIM 8192
#define D_DIM 128

typedef __attribute__((ext_vector_type(8))) __bf16 bf16x8;
typedef __attribute__((ext_vector_type(4))) float f32x4;

__device__ __forceinline__ unsigned short f2bf(float f) {
    unsigned u = __builtin_bit_cast(unsigned, f);
    unsigned r = (u + 0x7FFFu + ((u >> 16) & 1u)) >> 16;
    return (unsigned short)r;
}

__device__ __forceinline__ float gelu_tanh(float x) {
    const float c = 0.7978845608028654f; // sqrt(2/pi)
    float u = c * (x + 0.044715f * x * x * x);
    float e = __expf(2.0f * u);
    float th = 1.0f - 2.0f / (e + 1.0f);
    return 0.5f * x * (1.0f + th);
}

__device__ __forceinline__ float softplus_f(float x) {
    return (x > 20.0f) ? x : log1pf(__expf(x));
}

template<int CTRL>
__device__ __forceinline__ float maxdpp(float v) {
    int t = __builtin_amdgcn_update_dpp(0, __builtin_bit_cast(int, v), CTRL, 0xF, 0xF, true);
    return fmaxf(v, __builtin_bit_cast(float, t));
}
// max across the 16 lanes of a lane-group (lanes l&~15 .. |15)
__device__ __forceinline__ float rowmax16(float v) {
    v = maxdpp<0xB1>(v);   // quad_perm [1,0,3,2]  (xor 1)
    v = maxdpp<0x4E>(v);   // quad_perm [2,3,0,1]  (xor 2)
    v = maxdpp<0x141>(v);  // row_half_mirror      (xor 7)
    v = maxdpp<0x140>(v);  // row_mirror           (xor 15)
    return v;
}

// one wave per row: gelu, normalize, write on (row-major) + V^T (transposed)
__global__ __launch_bounds__(256) void prep_kernel(
    const float* __restrict__ x,
    unsigned short* __restrict__ on,
    unsigned short* __restrict__ vT)
{
    const int row = blockIdx.x * 4 + (threadIdx.x >> 6);
    const int lane = threadIdx.x & 63;
    const float2 xv = *reinterpret_cast<const float2*>(x + (size_t)row * D_DIM + lane * 2);
    float g0 = gelu_tanh(xv.x), g1 = gelu_tanh(xv.y);
    float ss = g0 * g0 + g1 * g1;
    #pragma unroll
    for (int m = 1; m < 64; m <<= 1) ss += __shfl_xor(ss, m, 64);
    float inv = 1.0f / fmaxf(sqrtf(ss), 1e-6f);
    unsigned pack = ((unsigned)f2bf(g1 * inv) << 16) | f2bf(g0 * inv);
    *reinterpret_cast<unsigned*>(on + (size_t)row * D_DIM + lane * 2) = pack;
    const int b = row >> 13, t = row & (T_DIM - 1);
    size_t vb = (size_t)b * D_DIM * T_DIM + (size_t)(lane * 2) * T_DIM + t;
    vT[vb] = f2bf(g0);
    vT[vb + T_DIM] = f2bf(g1);
}

// flash attention: block = 16 q-rows, 4 waves split the KV range, LDS combine
__global__ __launch_bounds__(256, 2) void attn_kernel(
    const float* __restrict__ x,
    const unsigned short* __restrict__ on,
    const unsigned short* __restrict__ vT,
    const float* __restrict__ lbr,
    const float* __restrict__ lar,
    float* __restrict__ out)
{
    __shared__ unsigned short p_lds[4][16 * 40]; // padded stride 40 (bank spread)
    __shared__ float obuf[4][16][128];
    __shared__ float mbuf[4][16];
    __shared__ float lbuf[4][16];

    const int tid = threadIdx.x;
    const int wave = tid >> 6;
    const int lane = tid & 63;
    const int g = lane >> 4;   // 0..3
    const int c = lane & 15;   // 0..15

    const int batch = blockIdx.x & 1;
    const int tile = blockIdx.x >> 1;
    const int q0 = (T_DIM - 16) - tile * 16;   // longest tiles first

    const float beta = fminf(softplus_f(lbr[0]), 5.0f) + 0.5f;
    const float sc = beta * 0.08838834764831843f; // beta / sqrt(128)
    const float alpha = softplus_f(lar[0]);

    const unsigned short* onb = on + (size_t)batch * T_DIM * D_DIM;
    const unsigned short* vTb = vT + (size_t)batch * D_DIM * T_DIM;

    // Q fragments: A[row=c][k = dc*32 + g*8 + j]
    bf16x8 qf[4];
    #pragma unroll
    for (int dc = 0; dc < 4; ++dc)
        qf[dc] = *reinterpret_cast<const bf16x8*>(onb + (size_t)(q0 + c) * D_DIM + dc * 32 + g * 8);

    bf16x8 ones;
    #pragma unroll
    for (int j = 0; j < 8; ++j) ones[j] = (__bf16)1.0f;

    f32x4 acc[8];
    #pragma unroll
    for (int dt = 0; dt < 8; ++dt) acc[dt] = (f32x4){0.f, 0.f, 0.f, 0.f};
    f32x4 accl = (f32x4){0.f, 0.f, 0.f, 0.f};
    float mrow[4] = {-1e30f, -1e30f, -1e30f, -1e30f};

    const int NC = (q0 + 16 + 31) >> 5;         // # of 32-key chunks
    const int it0 = (NC * wave) >> 2;           // this wave's KV slice
    const int it1 = (NC * (wave + 1)) >> 2;

    for (int it = it0; it < it1; ++it) {
        const int kb = it << 5;
        // ---- QK^T: S[q=(g*4+r)][key=c(+16)] ----
        f32x4 s0 = (f32x4){0.f, 0.f, 0.f, 0.f}, s1 = (f32x4){0.f, 0.f, 0.f, 0.f};
        #pragma unroll
        for (int dc = 0; dc < 4; ++dc) {
            bf16x8 k0 = *reinterpret_cast<const bf16x8*>(onb + (size_t)(kb + c) * D_DIM + dc * 32 + g * 8);
            bf16x8 k1 = *reinterpret_cast<const bf16x8*>(onb + (size_t)(kb + 16 + c) * D_DIM + dc * 32 + g * 8);
            s0 = __builtin_amdgcn_mfma_f32_16x16x32_bf16(qf[dc], k0, s0, 0, 0, 0);
            s1 = __builtin_amdgcn_mfma_f32_16x16x32_bf16(qf[dc], k1, s1, 0, 0, 0);
        }
        // ---- online softmax (DPP row-max; row-sum via MFMA-with-ones) ----
        #pragma unroll
        for (int r = 0; r < 4; ++r) {
            const int q = q0 + g * 4 + r;
            float v0 = (kb + c <= q) ? s0[r] * sc : -INFINITY;
            float v1 = (kb + 16 + c <= q) ? s1[r] * sc : -INFINITY;
            float mx = rowmax16(fmaxf(v0, v1));
            float mnew = fmaxf(mrow[r], mx);
            float fac = __expf(mrow[r] - mnew);
            mrow[r] = mnew;
            float p0 = __expf(v0 - mnew);
            float p1 = __expf(v1 - mnew);
            #pragma unroll
            for (int dt = 0; dt < 8; ++dt) acc[dt][r] *= fac;
            accl[r] *= fac;
            p_lds[wave][(g * 4 + r) * 40 + c] = f2bf(p0);
            p_lds[wave][(g * 4 + r) * 40 + c + 16] = f2bf(p1);
        }
        // ---- PV: A = P from LDS (same-wave DS ops are in-order) ----
        bf16x8 pa = *reinterpret_cast<const bf16x8*>(&p_lds[wave][c * 40 + g * 8]);
        accl = __builtin_amdgcn_mfma_f32_16x16x32_bf16(pa, ones, accl, 0, 0, 0);
        #pragma unroll
        for (int dt = 0; dt < 8; ++dt) {
            bf16x8 vf = *reinterpret_cast<const bf16x8*>(vTb + (size_t)(dt * 16 + c) * T_DIM + kb + g * 8);
            acc[dt] = __builtin_amdgcn_mfma_f32_16x16x32_bf16(pa, vf, acc[dt], 0, 0, 0);
        }
    }

    // ---- write partials, combine across 4 waves ----
    #pragma unroll
    for (int dt = 0; dt < 8; ++dt)
        #pragma unroll
        for (int r = 0; r < 4; ++r)
            obuf[wave][g * 4 + r][dt * 16 + c] = acc[dt][r];
    if (c == 0) {
        #pragma unroll
        for (int r = 0; r < 4; ++r) {
            mbuf[wave][g * 4 + r] = mrow[r];
            lbuf[wave][g * 4 + r] = accl[r];
        }
    }
    __syncthreads();

    const int row = tid >> 4;
    const int d0 = (tid & 15) * 8;
    float m0 = mbuf[0][row], m1 = mbuf[1][row], m2 = mbuf[2][row], m3 = mbuf[3][row];
    float M = fmaxf(fmaxf(m0, m1), fmaxf(m2, m3));
    float w0 = __expf(m0 - M), w1 = __expf(m1 - M), w2 = __expf(m2 - M), w3 = __expf(m3 - M);
    float L = w0 * lbuf[0][row] + w1 * lbuf[1][row] + w2 * lbuf[2][row] + w3 * lbuf[3][row];
    float invL = 1.0f / L;
    const size_t gbase = ((size_t)batch * T_DIM + q0 + row) * D_DIM + d0;
    #pragma unroll
    for (int i = 0; i < 8; ++i) {
        float num = w0 * obuf[0][row][d0 + i] + w1 * obuf[1][row][d0 + i]
                  + w2 * obuf[2][row][d0 + i] + w3 * obuf[3][row][d0 + i];
        float mu = num * invL;
        float gv = gelu_tanh(x[gbase + i]);
        out[gbase + i] = gv + alpha * (gv - mu);
    }
}

extern "C" void kernel_launch(void* const* d_in, const int* in_sizes, int n_in,
                              void* d_out, int out_size, void* d_ws, size_t ws_size,
                              hipStream_t stream) {
    const float* x = (const float*)d_in[0];
    const float* lbr = (const float*)d_in[1];
    const float* lar = (const float*)d_in[2];
    float* out = (float*)d_out;

    unsigned short* on = (unsigned short*)d_ws;                       // 2*T*D bf16 = 4 MiB
    unsigned short* vT = on + (size_t)2 * T_DIM * D_DIM;              // 2*D*T bf16 = 4 MiB

    prep_kernel<<<dim3((2 * T_DIM) / 4), dim3(256), 0, stream>>>(x, on, vT);
    attn_kernel<<<dim3((2 * T_DIM) / 16), dim3(256), 0, stream>>>(x, on, vT, lbr, lar, out);
}

// Round 2
// 127.003 us; speedup vs baseline: 2.4204x; 2.4204x over previous
//
#include <hip/hip_runtime.h>
#include <hip/hip_bf16.h>
#include <math.h>

#define T_DIM 8192
#define D_DIM 128

typedef __attribute__((ext_vector_type(8))) __bf16 bf16x8;
typedef __attribute__((ext_vector_type(2))) __bf16 bf16x2;
typedef __attribute__((ext_vector_type(4))) float f32x4;

static __device__ __forceinline__ unsigned short f2bf(float f) {
    unsigned u = __builtin_bit_cast(unsigned, f);
    unsigned r = (u + 0x7FFFu + ((u >> 16) & 1u)) >> 16;
    return (unsigned short)r;
}

static __device__ __forceinline__ float gelu_tanh(float x) {
    const float c = 0.7978845608028654f; // sqrt(2/pi)
    float u = c * (x + 0.044715f * x * x * x);
    float e = __expf(2.0f * u);
    float th = 1.0f - 2.0f / (e + 1.0f);
    return 0.5f * x * (1.0f + th);
}

static __device__ __forceinline__ float softplus_f(float x) {
    return (x > 20.0f) ? x : log1pf(__expf(x));
}

// one wave per row: gelu, normalize, write on (row-major bf16) + V^T (bf16)
__global__ __launch_bounds__(256) void prep_kernel(
    const float* __restrict__ x,
    unsigned short* __restrict__ on,
    unsigned short* __restrict__ vT)
{
    const int row = blockIdx.x * 4 + (threadIdx.x >> 6);
    const int lane = threadIdx.x & 63;
    const float2 xv = *reinterpret_cast<const float2*>(x + (size_t)row * D_DIM + lane * 2);
    float g0 = gelu_tanh(xv.x), g1 = gelu_tanh(xv.y);
    float ss = g0 * g0 + g1 * g1;
    #pragma unroll
    for (int m = 1; m < 64; m <<= 1) ss += __shfl_xor(ss, m, 64);
    float inv = 1.0f / fmaxf(sqrtf(ss), 1e-6f);
    unsigned pack = ((unsigned)f2bf(g1 * inv) << 16) | f2bf(g0 * inv);
    *reinterpret_cast<unsigned*>(on + (size_t)row * D_DIM + lane * 2) = pack;
    const int b = row >> 13, t = row & (T_DIM - 1);
    size_t vb = (size_t)b * D_DIM * T_DIM + (size_t)(lane * 2) * T_DIM + t;
    vT[vb] = f2bf(g0);
    vT[vb + T_DIM] = f2bf(g1);
}

// block = 64 q-rows (4 waves x 16), all waves share one KV segment staged in LDS.
// No softmax max-tracking (|logit| <= beta/sqrt(D) <= 0.49 structurally, exp safe).
__global__ __launch_bounds__(256, 3) void attn_kernel(
    const float* __restrict__ x,
    const unsigned short* __restrict__ on,
    const unsigned short* __restrict__ vT,
    const float* __restrict__ lbr,
    const float* __restrict__ lar,
    float* __restrict__ partO,
    float* __restrict__ partL,
    float* __restrict__ out,
    int MS)
{
    __shared__ unsigned short ks[2][32 * 128];   // K tiles [row 0..31][d 0..127], XOR-swizzled
    __shared__ unsigned short vs[2][128 * 32];   // V tiles [d 0..127][key 0..31], XOR-swizzled
    __shared__ unsigned short p_lds[4][16 * 40]; // per-wave P, stride 40 u16 (80B)
    __shared__ float lbuf[64];

    const int tile = blockIdx.x >> 1;
    const int batch = blockIdx.x & 1;
    const int q0 = 8128 - 64 * tile;            // longest-first
    const int R = q0 + 64;
    int nseg = (R + 2047) >> 11; if (nseg > MS) nseg = MS;
    const int seg = blockIdx.y;
    if (seg >= nseg) return;
    int len = ((R + nseg - 1) / nseg + 31) & ~31;
    const int s0 = seg * len;
    int s1 = s0 + len; if (s1 > R) s1 = R;
    const int nit = (s1 - s0) >> 5;

    const int tid = threadIdx.x;
    const int w = tid >> 6, lane = tid & 63, g = lane >> 4, c = lane & 15;
    const int qw0 = q0 + 16 * w;
    const int qrow = qw0 + c;

    const float beta = fminf(softplus_f(lbr[0]), 5.0f) + 0.5f;
    const float sc = beta * 0.08838834764831843f; // beta / sqrt(128)

    const unsigned short* onb = on + (size_t)batch * T_DIM * D_DIM;
    const unsigned short* vTb = vT + (size_t)batch * D_DIM * T_DIM;

    // Q fragments (B operand): B[k=g*8+j][col=c] = on[qw0+c][dc*32+g*8+j]
    bf16x8 qf[4];
    #pragma unroll
    for (int dc = 0; dc < 4; ++dc)
        qf[dc] = *reinterpret_cast<const bf16x8*>(onb + (size_t)qrow * D_DIM + dc * 32 + g * 8);

    // staging geometry (constant per thread): 512 16B chunks each for K and V
    const int krow0 = tid >> 4, kcol0 = tid & 15;         // + chunk at krow0+16
    const int klog0 = kcol0 ^ (krow0 & 7);                // logical chunk (same for both)
    const int vrow0 = tid >> 2, vslot0 = tid & 3;         // + chunk at vrow0+64
    const int vlog0 = vslot0 ^ ((vrow0 >> 1) & 3);

    f32x4 acc[8];
    #pragma unroll
    for (int dt = 0; dt < 8; ++dt) acc[dt] = (f32x4){0.f, 0.f, 0.f, 0.f};
    float lsum = 0.0f;

    const int kswz = c & 7;
    const int vswz = (c >> 1) & 3;

    uint4 kr0, kr1, vr0, vr1;
#define LD(KB) { \
    kr0 = *reinterpret_cast<const uint4*>(onb + (size_t)((KB) + krow0) * D_DIM + klog0 * 8); \
    kr1 = *reinterpret_cast<const uint4*>(onb + (size_t)((KB) + krow0 + 16) * D_DIM + klog0 * 8); \
    vr0 = *reinterpret_cast<const uint4*>(vTb + (size_t)vrow0 * T_DIM + (KB) + vlog0 * 8); \
    vr1 = *reinterpret_cast<const uint4*>(vTb + (size_t)(vrow0 + 64) * T_DIM + (KB) + vlog0 * 8); }
#define ST(CUR) { \
    *reinterpret_cast<uint4*>(&ks[CUR][krow0 * 128 + kcol0 * 8]) = kr0; \
    *reinterpret_cast<uint4*>(&ks[CUR][(krow0 + 16) * 128 + kcol0 * 8]) = kr1; \
    *reinterpret_cast<uint4*>(&vs[CUR][vrow0 * 32 + vslot0 * 8]) = vr0; \
    *reinterpret_cast<uint4*>(&vs[CUR][(vrow0 + 64) * 32 + vslot0 * 8]) = vr1; }

    LD(s0); ST(0);
    int cur = 0;

    for (int it = 0; it < nit; ++it) {
        const int kb = s0 + (it << 5);
        __syncthreads();                 // buf[cur] visible to all
        if (it + 1 < nit) LD(kb + 32);   // issue next loads early (hide latency)

        if (kb <= qw0 + 15) {            // wave-uniform: some key valid for this wave
            // ---- QK^T swapped: A=K, B=Q -> s[t][r] = S[key=kb+16t+g*4+r][q=qrow]
            f32x4 st0 = (f32x4){0.f,0.f,0.f,0.f}, st1 = (f32x4){0.f,0.f,0.f,0.f};
            #pragma unroll
            for (int dc = 0; dc < 4; ++dc) {
                bf16x8 kf0 = *reinterpret_cast<const bf16x8*>(
                    &ks[cur][(c) * 128 + (((dc * 4 + g) ^ kswz) * 8)]);
                bf16x8 kf1 = *reinterpret_cast<const bf16x8*>(
                    &ks[cur][(16 + c) * 128 + (((dc * 4 + g) ^ kswz) * 8)]);
                st0 = __builtin_amdgcn_mfma_f32_16x16x32_bf16(kf0, qf[dc], st0, 0, 0, 0);
                st1 = __builtin_amdgcn_mfma_f32_16x16x32_bf16(kf1, qf[dc], st1, 0, 0, 0);
            }
            // ---- softmax, fixed max=0: p = exp(sc*s), masked to 0
            #pragma unroll
            for (int t = 0; t < 2; ++t) {
                const f32x4 stv = t ? st1 : st0;
                float p[4];
                #pragma unroll
                for (int r = 0; r < 4; ++r) {
                    const int key = kb + 16 * t + g * 4 + r;
                    float pv = __expf(stv[r] * sc);
                    p[r] = (key <= qrow) ? pv : 0.0f;
                    lsum += p[r];
                }
                bf16x2 w0, w1;
                w0[0] = (__bf16)p[0]; w0[1] = (__bf16)p[1];
                w1[0] = (__bf16)p[2]; w1[1] = (__bf16)p[3];
                uint2 pk;
                pk.x = __builtin_bit_cast(unsigned, w0);
                pk.y = __builtin_bit_cast(unsigned, w1);
                *reinterpret_cast<uint2*>(
                    reinterpret_cast<char*>(&p_lds[w][0]) + c * 80 + t * 32 + g * 8) = pk;
            }
            // ---- PV: A = P[q=c][key g*8..g*8+7], B = V
            bf16x8 pa = *reinterpret_cast<const bf16x8*>(
                reinterpret_cast<char*>(&p_lds[w][0]) + c * 80 + g * 16);
            #pragma unroll
            for (int dt = 0; dt < 8; ++dt) {
                const int vrow = dt * 16 + c;
                bf16x8 vf = *reinterpret_cast<const bf16x8*>(
                    &vs[cur][vrow * 32 + ((g ^ vswz) * 8)]);
                acc[dt] = __builtin_amdgcn_mfma_f32_16x16x32_bf16(pa, vf, acc[dt], 0, 0, 0);
            }
        }
        if (it + 1 < nit) ST(cur ^ 1);   // write next buf (waits its own loads only)
        cur ^= 1;
    }
#undef LD
#undef ST

    // full row-sum: reduce lsum over the 4 g-groups (lanes xor 16, 32)
    lsum += __shfl_xor(lsum, 16, 64);
    lsum += __shfl_xor(lsum, 32, 64);

    if (nseg > 1) {
        const size_t slot = (size_t)blockIdx.x * MS + seg;
        float* po = partO + slot * 8192;
        #pragma unroll
        for (int dt = 0; dt < 8; ++dt)
            #pragma unroll
            for (int r = 0; r < 4; ++r)
                po[(w * 16 + g * 4 + r) * 128 + dt * 16 + c] = acc[dt][r];
        if (lane < 16) partL[slot * 64 + w * 16 + lane] = lsum;
    } else {
        // direct epilogue (single segment covers the whole causal range)
        if (lane < 16) lbuf[w * 16 + lane] = lsum;
        __syncthreads();
        const float alpha = softplus_f(lar[0]);
        #pragma unroll
        for (int dt = 0; dt < 8; ++dt)
            #pragma unroll
            for (int r = 0; r < 4; ++r) {
                const int qr = 16 * w + g * 4 + r;
                const float L = lbuf[qr];
                const float mu = acc[dt][r] / L;
                const size_t gi = ((size_t)batch * T_DIM + q0 + qr) * D_DIM + dt * 16 + c;
                const float gv = gelu_tanh(x[gi]);
                out[gi] = gv + alpha * (gv - mu);
            }
    }
}

// combine segment partials (plain add) + epilogue
__global__ __launch_bounds__(256) void reduce_kernel(
    const float* __restrict__ x,
    const float* __restrict__ lar,
    const float* __restrict__ partO,
    const float* __restrict__ partL,
    float* __restrict__ out,
    int MS)
{
    const int idx = blockIdx.x * 256 + threadIdx.x;   // 524288 threads, 4 floats each
    const int row = idx >> 5;
    const int d0 = (idx & 31) << 2;
    const int batch = row >> 13, qq = row & 8191;
    const int tile = 127 - (qq >> 6);
    const int R = 8192 - 64 * tile;
    int nseg = (R + 2047) >> 11; if (nseg > MS) nseg = MS;
    if (nseg <= 1) return;                            // written directly by attn
    const int roff = qq & 63;
    const int t_lin = (tile << 1) | batch;

    f32x4 o = (f32x4){0.f, 0.f, 0.f, 0.f};
    float L = 0.0f;
    for (int s = 0; s < nseg; ++s) {
        const size_t slot = (size_t)t_lin * MS + s;
        o += *reinterpret_cast<const f32x4*>(partO + slot * 8192 + roff * 128 + d0);
        L += partL[slot * 64 + roff];
    }
    const float invL = 1.0f / L;
    const float alpha = softplus_f(lar[0]);
    const size_t gi = (size_t)row * D_DIM + d0;
    const f32x4 xv = *reinterpret_cast<const f32x4*>(x + gi);
    f32x4 ov;
    #pragma unroll
    for (int j = 0; j < 4; ++j) {
        const float gv = gelu_tanh(xv[j]);
        ov[j] = gv + alpha * (gv - o[j] * invL);
    }
    *reinterpret_cast<f32x4*>(out + gi) = ov;
}

extern "C" void kernel_launch(void* const* d_in, const int* in_sizes, int n_in,
                              void* d_out, int out_size, void* d_ws, size_t ws_size,
                              hipStream_t stream) {
    const float* x = (const float*)d_in[0];
    const float* lbr = (const float*)d_in[1];
    const float* lar = (const float*)d_in[2];
    float* out = (float*)d_out;

    unsigned short* on = (unsigned short*)d_ws;                 // 4 MiB bf16
    unsigned short* vT = on + (size_t)2 * T_DIM * D_DIM;        // 4 MiB bf16
    const size_t fixed = (size_t)8 * 1024 * 1024;
    float* partO = (float*)((char*)d_ws + fixed);
    const size_t per_seg = 256ull * (8192 + 64) * 4;            // ~8.45 MiB per segment level
    size_t avail = ws_size > fixed ? ws_size - fixed : 0;
    int MS = (int)(avail / per_seg);
    if (MS > 4) MS = 4;
    if (MS < 1) MS = 1;
    float* partL = partO + (size_t)256 * MS * 8192;

    prep_kernel<<<dim3((2 * T_DIM) / 4), dim3(256), 0, stream>>>(x, on, vT);
    attn_kernel<<<dim3(256, MS), dim3(256), 0, stream>>>(x, on, vT, lbr, lar,
                                                         partO, partL, out, MS);
    if (MS > 1)
        reduce_kernel<<<dim3(2048), dim3(256), 0, stream>>>(x, lar, partO, partL, out, MS);
}

// Round 3
// 89.072 us; speedup vs baseline: 3.4511x; 1.4258x over previous
//
#include <hip/hip_runtime.h>
#include <hip/hip_bf16.h>
#include <math.h>

#define T_DIM 8192
#define D_DIM 128

typedef __attribute__((ext_vector_type(8))) __bf16 bf16x8;
typedef __attribute__((ext_vector_type(16))) float f32x16;
typedef __attribute__((ext_vector_type(4))) float f32x4;

static __device__ __forceinline__ unsigned short f2bf(float f) {
    unsigned u = __builtin_bit_cast(unsigned, f);
    unsigned r = (u + 0x7FFFu + ((u >> 16) & 1u)) >> 16;
    return (unsigned short)r;
}
static __device__ __forceinline__ float bf2f(unsigned short h) {
    unsigned u = ((unsigned)h) << 16;
    return __builtin_bit_cast(float, u);
}

static __device__ __forceinline__ float gelu_tanh(float x) {
    const float c = 0.7978845608028654f; // sqrt(2/pi)
    float u = c * (x + 0.044715f * x * x * x);
    float e = __expf(2.0f * u);
    float th = 1.0f - 2.0f / (e + 1.0f);
    return 0.5f * x * (1.0f + th);
}
static __device__ __forceinline__ float softplus_f(float x) {
    return (x > 20.0f) ? x : log1pf(__expf(x));
}

// ---------------------------------------------------------------------------
// prep: gelu, row-normalize -> on (row-major bf16); raw gelu -> vT' transposed
// with per-32-block column permutation sigma(k) = swap bits 2<->3 (involution).
// Block = 32 key-rows x 128 d.
// ---------------------------------------------------------------------------
__global__ __launch_bounds__(256) void prep_kernel(
    const float* __restrict__ x,
    unsigned short* __restrict__ on,
    unsigned short* __restrict__ vT)
{
    __shared__ unsigned short vt[32 * 128];   // [key-row][d], raw gelu bf16
    const int blk = blockIdx.x;               // 512 blocks
    const int batch = blk >> 8;
    const int kb32 = (blk & 255) << 5;
    const int t = threadIdx.x;
    const int r = t >> 3;
    const int d0 = (t & 7) << 4;

    const size_t rowbase = ((size_t)batch * T_DIM + kb32 + r) * D_DIM;
    float g[16];
    #pragma unroll
    for (int i = 0; i < 16; i += 4) {
        f32x4 xv = *reinterpret_cast<const f32x4*>(x + rowbase + d0 + i);
        g[i+0] = gelu_tanh(xv[0]); g[i+1] = gelu_tanh(xv[1]);
        g[i+2] = gelu_tanh(xv[2]); g[i+3] = gelu_tanh(xv[3]);
    }
    float ss = 0.f;
    #pragma unroll
    for (int i = 0; i < 16; ++i) ss += g[i] * g[i];
    ss += __shfl_xor(ss, 1, 64); ss += __shfl_xor(ss, 2, 64); ss += __shfl_xor(ss, 4, 64);
    const float inv = 1.0f / fmaxf(sqrtf(ss), 1e-6f);

    unsigned pk[8], vp[8];
    #pragma unroll
    for (int i = 0; i < 8; ++i) {
        pk[i] = (unsigned)f2bf(g[2*i] * inv) | ((unsigned)f2bf(g[2*i+1] * inv) << 16);
        vp[i] = (unsigned)f2bf(g[2*i])       | ((unsigned)f2bf(g[2*i+1]) << 16);
    }
    uint4 oa = {pk[0],pk[1],pk[2],pk[3]}, ob = {pk[4],pk[5],pk[6],pk[7]};
    *reinterpret_cast<uint4*>(on + rowbase + d0)     = oa;
    *reinterpret_cast<uint4*>(on + rowbase + d0 + 8) = ob;
    uint4 va = {vp[0],vp[1],vp[2],vp[3]}, vb = {vp[4],vp[5],vp[6],vp[7]};
    *reinterpret_cast<uint4*>(&vt[r * 128 + d0])     = va;
    *reinterpret_cast<uint4*>(&vt[r * 128 + d0 + 8]) = vb;

    __syncthreads();

    // write vT'[d][kb32 + pos], pos p holds key sigma(p) (swap bits 2,3)
    const int dd = t >> 1, h = (t & 1) * 16;
    unsigned short vals[16];
    #pragma unroll
    for (int j = 0; j < 16; ++j) {
        const int sj = (j & 3) | ((j & 4) << 1) | ((j & 8) >> 1);
        vals[j] = vt[(h + sj) * 128 + dd];
    }
    unsigned wp[8];
    #pragma unroll
    for (int i = 0; i < 8; ++i)
        wp[i] = (unsigned)vals[2*i] | ((unsigned)vals[2*i+1] << 16);
    uint4 wa = {wp[0],wp[1],wp[2],wp[3]}, wb = {wp[4],wp[5],wp[6],wp[7]};
    unsigned short* dst = vT + (size_t)batch * D_DIM * T_DIM + (size_t)dd * T_DIM + kb32 + h;
    *reinterpret_cast<uint4*>(dst)     = wa;
    *reinterpret_cast<uint4*>(dst + 8) = wb;
}

// ---------------------------------------------------------------------------
// attn: block = 128 q-rows (4 waves x 32), 32x32x16 MFMA, KV double-buffered
// in LDS, softmax fully in registers (fixed max = 0), P -> PV A-frag is the
// QK accumulator in natural register order (V columns pre-permuted).
// ---------------------------------------------------------------------------
__global__ __launch_bounds__(256, 2) void attn_kernel(
    const float* __restrict__ x,
    const unsigned short* __restrict__ on,
    const unsigned short* __restrict__ vT,
    const float* __restrict__ lbr,
    const float* __restrict__ lar,
    unsigned short* __restrict__ partO,
    float* __restrict__ partL,
    float* __restrict__ out,
    int MS)
{
    __shared__ unsigned short ks[2][32 * 128]; // K tile [key][d], chunk-swizzled
    __shared__ unsigned short vs[2][128 * 32]; // V tile [d][slot], chunk-swizzled
    __shared__ float lbuf[128];

    const int bx = blockIdx.x;
    const int batch = bx & 1, tl = bx >> 1;
    const int q0 = 8064 - 128 * tl;            // longest-first
    const int R = q0 + 128;
    int nseg = (R + 1023) >> 10; if (nseg > MS) nseg = MS;
    const int seg = blockIdx.y;
    if (seg >= nseg) return;
    const int len = (((R + nseg - 1) / nseg) + 31) & ~31;
    const int s0 = seg * len;
    int s1 = s0 + len; if (s1 > R) s1 = R;
    const int nit = (s1 - s0) >> 5;

    const int tid = threadIdx.x;
    const int w = tid >> 6, lane = tid & 63;
    const int hi = lane >> 5, cc = lane & 31;
    const int qw0 = q0 + 32 * w;

    const float beta = fminf(softplus_f(lbr[0]), 5.0f) + 0.5f;
    const float sc = beta * 0.08838834764831843f;   // beta / sqrt(128)

    const unsigned short* onb = on + (size_t)batch * T_DIM * D_DIM;
    const unsigned short* vTb = vT + (size_t)batch * D_DIM * T_DIM;

    // Q B-fragments: B[k=hi*8+j][col=cc] = on[qw0+cc][dc*16 + hi*8 + j]
    bf16x8 qf[8];
    #pragma unroll
    for (int dc = 0; dc < 8; ++dc)
        qf[dc] = *reinterpret_cast<const bf16x8*>(onb + (size_t)(qw0 + cc) * D_DIM + dc*16 + hi*8);

    f32x16 acc[4];
    #pragma unroll
    for (int dt = 0; dt < 4; ++dt)
        #pragma unroll
        for (int ri = 0; ri < 16; ++ri) acc[dt][ri] = 0.f;
    float lsum = 0.f;

    // read-side swizzle constants
    const int ke = hi ^ (cc & 7);         // K chunk xor
    const int vf_ = hi ^ ((cc >> 1) & 3); // V chunk xor

    // staging geometry
    const int krow  = tid >> 3;
    const int kposA = tid & 7;
    const int kchA  = kposA ^ (krow & 7);
    const unsigned short* kptr = onb + (size_t)(s0 + krow) * D_DIM + kchA * 8;
    const int kdst = krow * 128 + kposA * 8;

    const int vd    = tid >> 1;
    const int vposA = (tid & 1) * 2;
    const int vsw   = (vd >> 1) & 3;
    const unsigned short* vptrA = vTb + (size_t)vd * T_DIM + s0 + (vposA ^ vsw) * 8;
    const unsigned short* vptrB = vTb + (size_t)vd * T_DIM + s0 + ((vposA + 1) ^ vsw) * 8;
    const int vdst = vd * 32 + vposA * 8;

    uint4 kr0, kr1, vr0, vr1;
    // prologue: stage tile 0
    kr0 = *reinterpret_cast<const uint4*>(kptr);
    kr1 = *reinterpret_cast<const uint4*>(kptr + 64);
    vr0 = *reinterpret_cast<const uint4*>(vptrA);
    vr1 = *reinterpret_cast<const uint4*>(vptrB);
    kptr += 32 * D_DIM; vptrA += 32; vptrB += 32;
    *reinterpret_cast<uint4*>(&ks[0][kdst])      = kr0;
    *reinterpret_cast<uint4*>(&ks[0][kdst + 64]) = kr1;
    *reinterpret_cast<uint4*>(&vs[0][vdst])      = vr0;
    *reinterpret_cast<uint4*>(&vs[0][vdst + 8])  = vr1;

    for (int it = 0; it < nit; ++it) {
        const int kb = s0 + (it << 5);
        const int b = it & 1;
        __syncthreads();
        if (it + 1 < nit) {   // issue next-tile loads early
            kr0 = *reinterpret_cast<const uint4*>(kptr);
            kr1 = *reinterpret_cast<const uint4*>(kptr + 64);
            vr0 = *reinterpret_cast<const uint4*>(vptrA);
            vr1 = *reinterpret_cast<const uint4*>(vptrB);
            kptr += 32 * D_DIM; vptrA += 32; vptrB += 32;
        }
        if (kb <= qw0 + 31) {  // wave-uniform
            const unsigned short* ksb = &ks[b][0];
            const unsigned short* vsb = &vs[b][0];
            // QK^T swapped: A=K, B=Q -> s[ri] = S[key=kb+(ri&3)+8(ri>>2)+4hi][q=qw0+cc]
            f32x16 s;
            #pragma unroll
            for (int ri = 0; ri < 16; ++ri) s[ri] = 0.f;
            #pragma unroll
            for (int dc = 0; dc < 8; ++dc) {
                bf16x8 kf = *reinterpret_cast<const bf16x8*>(
                    ksb + cc * 128 + (((dc * 2) ^ ke) * 8));
                s = __builtin_amdgcn_mfma_f32_32x32x16_bf16(kf, qf[dc], s, 0, 0, 0);
            }
            // softmax (fixed max=0); pack P -> A-frags in natural reg order
            bf16x8 pa0, pa1;
            if (kb + 31 <= qw0) {          // fully-valid tile: no mask
                #pragma unroll
                for (int ri = 0; ri < 16; ++ri) {
                    float p = __expf(s[ri] * sc);
                    lsum += p;
                    if (ri < 8) pa0[ri] = (__bf16)p; else pa1[ri - 8] = (__bf16)p;
                }
            } else {                        // boundary tile: causal mask
                const int q = qw0 + cc;
                #pragma unroll
                for (int ri = 0; ri < 16; ++ri) {
                    const int key = kb + (ri & 3) + 8 * (ri >> 2) + 4 * hi;
                    float p = __expf(s[ri] * sc);
                    p = (key <= q) ? p : 0.f;
                    lsum += p;
                    if (ri < 8) pa0[ri] = (__bf16)p; else pa1[ri - 8] = (__bf16)p;
                }
            }
            // PV: A = P (regs), B = V[slot][d] from LDS
            #pragma unroll
            for (int dt = 0; dt < 4; ++dt) {
                const int rb = (dt * 32 + cc) * 32;
                bf16x8 vf0 = *reinterpret_cast<const bf16x8*>(vsb + rb + ((0 ^ vf_) * 8));
                bf16x8 vf1 = *reinterpret_cast<const bf16x8*>(vsb + rb + ((2 ^ vf_) * 8));
                acc[dt] = __builtin_amdgcn_mfma_f32_32x32x16_bf16(pa0, vf0, acc[dt], 0, 0, 0);
                acc[dt] = __builtin_amdgcn_mfma_f32_32x32x16_bf16(pa1, vf1, acc[dt], 0, 0, 0);
            }
        }
        if (it + 1 < nit) {   // write next buffer
            *reinterpret_cast<uint4*>(&ks[b ^ 1][kdst])      = kr0;
            *reinterpret_cast<uint4*>(&ks[b ^ 1][kdst + 64]) = kr1;
            *reinterpret_cast<uint4*>(&vs[b ^ 1][vdst])      = vr0;
            *reinterpret_cast<uint4*>(&vs[b ^ 1][vdst + 8])  = vr1;
        }
    }

    // L per q-column: reduce across hi halves
    lsum += __shfl_xor(lsum, 32, 64);

    const int tile_lin = tl * 2 + batch;
    if (nseg > 1) {
        const size_t slot = (size_t)tile_lin * MS + seg;
        unsigned short* po = partO + slot * (128 * 128);
        #pragma unroll
        for (int dt = 0; dt < 4; ++dt)
            #pragma unroll
            for (int ri = 0; ri < 16; ++ri) {
                const int qr = (ri & 3) + 8 * (ri >> 2) + 4 * hi;
                po[(32 * w + qr) * 128 + dt * 32 + cc] = f2bf(acc[dt][ri]);
            }
        if (lane < 32) partL[slot * 128 + 32 * w + cc] = lsum;
    } else {
        if (lane < 32) lbuf[w * 32 + cc] = lsum;
        const float alpha = softplus_f(lar[0]);
        #pragma unroll
        for (int dt = 0; dt < 4; ++dt)
            #pragma unroll
            for (int ri = 0; ri < 16; ++ri) {
                const int qr = (ri & 3) + 8 * (ri >> 2) + 4 * hi;
                const float L = lbuf[w * 32 + qr];
                const float mu = acc[dt][ri] / L;
                const size_t gi = ((size_t)batch * T_DIM + q0 + 32 * w + qr) * D_DIM + dt * 32 + cc;
                const float gv = gelu_tanh(x[gi]);
                out[gi] = gv + alpha * (gv - mu);
            }
    }
}

// ---------------------------------------------------------------------------
// reduce: sum bf16 partials (plain add across segments) + epilogue
// ---------------------------------------------------------------------------
__global__ __launch_bounds__(256) void reduce_kernel(
    const float* __restrict__ x,
    const float* __restrict__ lar,
    const unsigned short* __restrict__ partO,
    const float* __restrict__ partL,
    float* __restrict__ out,
    int MS)
{
    const int idx = blockIdx.x * 256 + threadIdx.x;  // 524288 threads
    const int row = idx >> 5;
    const int d0 = (idx & 31) << 2;
    const int batch = row >> 13, q = row & 8191;
    const int tl = 63 - (q >> 7);
    const int R = 8192 - 128 * tl;
    int nseg = (R + 1023) >> 10; if (nseg > MS) nseg = MS;
    if (nseg <= 1) return;                           // written directly by attn
    const int roff = q & 127;
    const int tile_lin = tl * 2 + batch;

    float o0 = 0.f, o1 = 0.f, o2 = 0.f, o3 = 0.f, L = 0.f;
    for (int s = 0; s < nseg; ++s) {
        const size_t slot = (size_t)tile_lin * MS + s;
        const unsigned short* po = partO + slot * (128 * 128) + roff * 128 + d0;
        o0 += bf2f(po[0]); o1 += bf2f(po[1]); o2 += bf2f(po[2]); o3 += bf2f(po[3]);
        L += partL[slot * 128 + roff];
    }
    const float invL = 1.0f / L;
    const float alpha = softplus_f(lar[0]);
    const size_t gi = (size_t)row * D_DIM + d0;
    const f32x4 xv = *reinterpret_cast<const f32x4*>(x + gi);
    f32x4 ov;
    const float mu[4] = {o0 * invL, o1 * invL, o2 * invL, o3 * invL};
    #pragma unroll
    for (int j = 0; j < 4; ++j) {
        const float gv = gelu_tanh(xv[j]);
        ov[j] = gv + alpha * (gv - mu[j]);
    }
    *reinterpret_cast<f32x4*>(out + gi) = ov;
}

extern "C" void kernel_launch(void* const* d_in, const int* in_sizes, int n_in,
                              void* d_out, int out_size, void* d_ws, size_t ws_size,
                              hipStream_t stream) {
    const float* x = (const float*)d_in[0];
    const float* lbr = (const float*)d_in[1];
    const float* lar = (const float*)d_in[2];
    float* out = (float*)d_out;

    unsigned short* on = (unsigned short*)d_ws;              // 4 MiB
    unsigned short* vT = on + (size_t)2 * T_DIM * D_DIM;     // 4 MiB
    const size_t fixed = (size_t)8 * 1024 * 1024;

    int MS = 1;
    if (ws_size > fixed + (1 << 20)) {
        const long long per = 128ll * (128 * 128 * 2 + 128 * 4); // po + partL per seg level
        long long avail = (long long)ws_size - (long long)fixed - (1 << 20);
        MS = (int)(avail / per);
        if (MS > 8) MS = 8;
        if (MS < 1) MS = 1;
    }
    unsigned short* partO = (unsigned short*)((char*)d_ws + fixed);
    float* partL = (float*)((char*)partO + (size_t)128 * MS * 128 * 128 * 2);

    prep_kernel<<<dim3(512), dim3(256), 0, stream>>>(x, on, vT);
    attn_kernel<<<dim3(128, MS), dim3(256), 0, stream>>>(x, on, vT, lbr, lar,
                                                         partO, partL, out, MS);
    if (MS > 1)
        reduce_kernel<<<dim3(2048), dim3(256), 0, stream>>>(x, lar, partO, partL, out, MS);
}

// Round 4
// 82.898 us; speedup vs baseline: 3.7082x; 1.0745x over previous
//
#include <hip/hip_runtime.h>
#include <hip/hip_bf16.h>
#include <math.h>

#define T_DIM 8192
#define D_DIM 128

typedef __attribute__((ext_vector_type(8))) __bf16 bf16x8;
typedef __attribute__((ext_vector_type(16))) float f32x16;
typedef __attribute__((ext_vector_type(4))) float f32x4;

static __device__ __forceinline__ unsigned short f2bf(float f) {
    unsigned u = __builtin_bit_cast(unsigned, f);
    unsigned r = (u + 0x7FFFu + ((u >> 16) & 1u)) >> 16;
    return (unsigned short)r;
}
static __device__ __forceinline__ float bf2f(unsigned short h) {
    unsigned u = ((unsigned)h) << 16;
    return __builtin_bit_cast(float, u);
}

static __device__ __forceinline__ float gelu_tanh(float x) {
    const float c = 0.7978845608028654f; // sqrt(2/pi)
    float u = c * (x + 0.044715f * x * x * x);
    float e = __expf(2.0f * u);
    float th = 1.0f - 2.0f / (e + 1.0f);
    return 0.5f * x * (1.0f + th);
}
static __device__ __forceinline__ float softplus_f(float x) {
    return (x > 20.0f) ? x : log1pf(__expf(x));
}

// ---------------------------------------------------------------------------
// prep: gelu, row-normalize -> on (row-major bf16); raw gelu -> vT' transposed
// with per-32-block column permutation sigma(k) = swap bits 2<->3 (involution).
// ---------------------------------------------------------------------------
__global__ __launch_bounds__(256) void prep_kernel(
    const float* __restrict__ x,
    unsigned short* __restrict__ on,
    unsigned short* __restrict__ vT)
{
    __shared__ unsigned short vt[32 * 128];   // [key-row][d], raw gelu bf16
    const int blk = blockIdx.x;               // 512 blocks
    const int batch = blk >> 8;
    const int kb32 = (blk & 255) << 5;
    const int t = threadIdx.x;
    const int r = t >> 3;
    const int d0 = (t & 7) << 4;

    const size_t rowbase = ((size_t)batch * T_DIM + kb32 + r) * D_DIM;
    float g[16];
    #pragma unroll
    for (int i = 0; i < 16; i += 4) {
        f32x4 xv = *reinterpret_cast<const f32x4*>(x + rowbase + d0 + i);
        g[i+0] = gelu_tanh(xv[0]); g[i+1] = gelu_tanh(xv[1]);
        g[i+2] = gelu_tanh(xv[2]); g[i+3] = gelu_tanh(xv[3]);
    }
    float ss = 0.f;
    #pragma unroll
    for (int i = 0; i < 16; ++i) ss += g[i] * g[i];
    ss += __shfl_xor(ss, 1, 64); ss += __shfl_xor(ss, 2, 64); ss += __shfl_xor(ss, 4, 64);
    const float inv = 1.0f / fmaxf(sqrtf(ss), 1e-6f);

    unsigned pk[8], vp[8];
    #pragma unroll
    for (int i = 0; i < 8; ++i) {
        pk[i] = (unsigned)f2bf(g[2*i] * inv) | ((unsigned)f2bf(g[2*i+1] * inv) << 16);
        vp[i] = (unsigned)f2bf(g[2*i])       | ((unsigned)f2bf(g[2*i+1]) << 16);
    }
    uint4 oa = {pk[0],pk[1],pk[2],pk[3]}, ob = {pk[4],pk[5],pk[6],pk[7]};
    *reinterpret_cast<uint4*>(on + rowbase + d0)     = oa;
    *reinterpret_cast<uint4*>(on + rowbase + d0 + 8) = ob;
    uint4 va = {vp[0],vp[1],vp[2],vp[3]}, vb = {vp[4],vp[5],vp[6],vp[7]};
    *reinterpret_cast<uint4*>(&vt[r * 128 + d0])     = va;
    *reinterpret_cast<uint4*>(&vt[r * 128 + d0 + 8]) = vb;

    __syncthreads();

    // write vT'[d][kb32 + pos], pos p holds key sigma(p) (swap bits 2,3)
    const int dd = t >> 1, h = (t & 1) * 16;
    unsigned short vals[16];
    #pragma unroll
    for (int j = 0; j < 16; ++j) {
        const int sj = (j & 3) | ((j & 4) << 1) | ((j & 8) >> 1);
        vals[j] = vt[(h + sj) * 128 + dd];
    }
    unsigned wp[8];
    #pragma unroll
    for (int i = 0; i < 8; ++i)
        wp[i] = (unsigned)vals[2*i] | ((unsigned)vals[2*i+1] << 16);
    uint4 wa = {wp[0],wp[1],wp[2],wp[3]}, wb = {wp[4],wp[5],wp[6],wp[7]};
    unsigned short* dst = vT + (size_t)batch * D_DIM * T_DIM + (size_t)dd * T_DIM + kb32 + h;
    *reinterpret_cast<uint4*>(dst)     = wa;
    *reinterpret_cast<uint4*>(dst + 8) = wb;
}

// ---------------------------------------------------------------------------
// attn: block = 128 q-rows (4 waves x 32), 32x32x16 MFMA, KV double-buffered
// in LDS, softmax in registers (fixed max = 0 -- |logit| <= 0.49 structurally),
// P -> PV A-frag is the QK accumulator in natural register order (V columns
// pre-permuted), row-sum L via MFMA with ones-B.
// ---------------------------------------------------------------------------
__global__ __launch_bounds__(256, 3) void attn_kernel(
    const float* __restrict__ x,
    const unsigned short* __restrict__ on,
    const unsigned short* __restrict__ vT,
    const float* __restrict__ lbr,
    const float* __restrict__ lar,
    unsigned short* __restrict__ partO,
    float* __restrict__ partL,
    float* __restrict__ out,
    int MS)
{
    __shared__ unsigned short ks[2][32 * 128]; // K tile [key][d], chunk-swizzled
    __shared__ unsigned short vs[2][128 * 32]; // V tile [d][slot], chunk-swizzled

    const int bx = blockIdx.x;
    const int batch = bx & 1, tl = bx >> 1;
    const int q0 = 8064 - 128 * tl;            // longest-first
    const int R = q0 + 128;
    int nseg = (R + 511) >> 9; if (nseg > MS) nseg = MS;
    const int seg = blockIdx.y;
    if (seg >= nseg) return;
    const int len = (((R + nseg - 1) / nseg) + 31) & ~31;
    const int s0 = seg * len;
    int s1 = s0 + len; if (s1 > R) s1 = R;
    const int nit = (s1 - s0) >> 5;

    const int tid = threadIdx.x;
    const int w = tid >> 6, lane = tid & 63;
    const int hi = lane >> 5, cc = lane & 31;
    const int qw0 = q0 + 32 * w;

    const float beta = fminf(softplus_f(lbr[0]), 5.0f) + 0.5f;
    const float sc = beta * 0.08838834764831843f;   // beta / sqrt(128)

    const unsigned short* onb = on + (size_t)batch * T_DIM * D_DIM;
    const unsigned short* vTb = vT + (size_t)batch * D_DIM * T_DIM;

    // Q B-fragments: B[k=hi*8+j][col=cc] = on[qw0+cc][dc*16 + hi*8 + j]
    bf16x8 qf[8];
    #pragma unroll
    for (int dc = 0; dc < 8; ++dc)
        qf[dc] = *reinterpret_cast<const bf16x8*>(onb + (size_t)(qw0 + cc) * D_DIM + dc*16 + hi*8);

    bf16x8 ones;
    #pragma unroll
    for (int j = 0; j < 8; ++j) ones[j] = (__bf16)1.0f;

    f32x16 acc[4], accl;
    #pragma unroll
    for (int dt = 0; dt < 4; ++dt)
        #pragma unroll
        for (int ri = 0; ri < 16; ++ri) acc[dt][ri] = 0.f;
    #pragma unroll
    for (int ri = 0; ri < 16; ++ri) accl[ri] = 0.f;

    // read-side swizzle constants
    const int ke = hi ^ (cc & 7);         // K chunk xor
    const int vf_ = hi ^ ((cc >> 1) & 3); // V chunk xor

    // K staging: thread -> rows (tid>>3, +16... actually krow covers 0..31)
    const int krow  = tid >> 3;
    const int kposA = tid & 7;
    const int kchA  = kposA ^ (krow & 7);
    const unsigned short* kptr = onb + (size_t)(s0 + krow) * D_DIM + kchA * 8;
    const int kdst = krow * 128 + kposA * 8;

    // V staging: thread (vd = tid&63, sel = tid>>6) writes rows vd and vd+64
    // at physical chunk p = sel ^ ((vd>>1)&3)  (conflict-free: 8 slots / 16 lanes)
    const int vd   = tid & 63;
    const int vsel = tid >> 6;
    const int vp   = vsel ^ ((vd >> 1) & 3);
    const unsigned short* vptrA = vTb + (size_t)vd * T_DIM + s0 + vsel * 8;
    const unsigned short* vptrB = vTb + (size_t)(vd + 64) * T_DIM + s0 + vsel * 8;
    const int vdstA = vd * 32 + vp * 8;
    const int vdstB = (vd + 64) * 32 + vp * 8;

    uint4 kr0, kr1, vr0, vr1;
    // prologue: stage tile 0
    kr0 = *reinterpret_cast<const uint4*>(kptr);
    kr1 = *reinterpret_cast<const uint4*>(kptr + 64);
    vr0 = *reinterpret_cast<const uint4*>(vptrA);
    vr1 = *reinterpret_cast<const uint4*>(vptrB);
    kptr += 32 * D_DIM; vptrA += 32; vptrB += 32;
    *reinterpret_cast<uint4*>(&ks[0][kdst])      = kr0;
    *reinterpret_cast<uint4*>(&ks[0][kdst + 64]) = kr1;
    *reinterpret_cast<uint4*>(&vs[0][vdstA])     = vr0;
    *reinterpret_cast<uint4*>(&vs[0][vdstB])     = vr1;

    for (int it = 0; it < nit; ++it) {
        const int kb = s0 + (it << 5);
        const int b = it & 1;
        __syncthreads();
        if (it + 1 < nit) {   // issue next-tile loads early
            kr0 = *reinterpret_cast<const uint4*>(kptr);
            kr1 = *reinterpret_cast<const uint4*>(kptr + 64);
            vr0 = *reinterpret_cast<const uint4*>(vptrA);
            vr1 = *reinterpret_cast<const uint4*>(vptrB);
            kptr += 32 * D_DIM; vptrA += 32; vptrB += 32;
        }
        if (kb <= qw0 + 31) {  // wave-uniform
            const unsigned short* ksb = &ks[b][0];
            const unsigned short* vsb = &vs[b][0];
            // QK^T swapped: A=K, B=Q -> s[ri] = S[key=kb+(ri&3)+8(ri>>2)+4hi][q=qw0+cc]
            f32x16 s;
            #pragma unroll
            for (int ri = 0; ri < 16; ++ri) s[ri] = 0.f;
            #pragma unroll
            for (int dc = 0; dc < 8; ++dc) {
                bf16x8 kf = *reinterpret_cast<const bf16x8*>(
                    ksb + cc * 128 + (((dc * 2) ^ ke) * 8));
                s = __builtin_amdgcn_mfma_f32_32x32x16_bf16(kf, qf[dc], s, 0, 0, 0);
            }
            // softmax (fixed max=0); pack P -> A-frags in natural reg order
            bf16x8 pa0, pa1;
            if (kb + 31 <= qw0) {          // fully-valid tile: no mask
                #pragma unroll
                for (int ri = 0; ri < 16; ++ri) {
                    float p = __expf(s[ri] * sc);
                    if (ri < 8) pa0[ri] = (__bf16)p; else pa1[ri - 8] = (__bf16)p;
                }
            } else {                        // boundary tile: causal mask
                const int q = qw0 + cc;
                #pragma unroll
                for (int ri = 0; ri < 16; ++ri) {
                    const int key = kb + (ri & 3) + 8 * (ri >> 2) + 4 * hi;
                    float p = __expf(s[ri] * sc);
                    p = (key <= q) ? p : 0.f;
                    if (ri < 8) pa0[ri] = (__bf16)p; else pa1[ri - 8] = (__bf16)p;
                }
            }
            // PV: A = P (regs), B = V[slot][d] from LDS; + ones-column for L
            accl = __builtin_amdgcn_mfma_f32_32x32x16_bf16(pa0, ones, accl, 0, 0, 0);
            accl = __builtin_amdgcn_mfma_f32_32x32x16_bf16(pa1, ones, accl, 0, 0, 0);
            #pragma unroll
            for (int dt = 0; dt < 4; ++dt) {
                const int rb = (dt * 32 + cc) * 32;
                bf16x8 vf0 = *reinterpret_cast<const bf16x8*>(vsb + rb + ((0 ^ vf_) * 8));
                bf16x8 vf1 = *reinterpret_cast<const bf16x8*>(vsb + rb + ((2 ^ vf_) * 8));
                acc[dt] = __builtin_amdgcn_mfma_f32_32x32x16_bf16(pa0, vf0, acc[dt], 0, 0, 0);
                acc[dt] = __builtin_amdgcn_mfma_f32_32x32x16_bf16(pa1, vf1, acc[dt], 0, 0, 0);
            }
        }
        if (it + 1 < nit) {   // write next buffer
            *reinterpret_cast<uint4*>(&ks[b ^ 1][kdst])      = kr0;
            *reinterpret_cast<uint4*>(&ks[b ^ 1][kdst + 64]) = kr1;
            *reinterpret_cast<uint4*>(&vs[b ^ 1][vdstA])     = vr0;
            *reinterpret_cast<uint4*>(&vs[b ^ 1][vdstB])     = vr1;
        }
    }

    const int tile_lin = tl * 2 + batch;
    if (nseg > 1) {
        const size_t slot = (size_t)tile_lin * MS + seg;
        unsigned short* po = partO + slot * (128 * 128);
        #pragma unroll
        for (int ri = 0; ri < 16; ++ri) {
            const int qr = (ri & 3) + 8 * (ri >> 2) + 4 * hi;
            #pragma unroll
            for (int dt = 0; dt < 4; ++dt)
                po[(32 * w + qr) * 128 + dt * 32 + cc] = f2bf(acc[dt][ri]);
        }
        if (cc == 0) {
            #pragma unroll
            for (int ri = 0; ri < 16; ++ri) {
                const int qr = (ri & 3) + 8 * (ri >> 2) + 4 * hi;
                partL[slot * 128 + 32 * w + qr] = accl[ri];
            }
        }
    } else {
        const float alpha = softplus_f(lar[0]);
        #pragma unroll
        for (int ri = 0; ri < 16; ++ri) {
            const int qr = (ri & 3) + 8 * (ri >> 2) + 4 * hi;
            const float invL = 1.0f / accl[ri];
            #pragma unroll
            for (int dt = 0; dt < 4; ++dt) {
                const float mu = acc[dt][ri] * invL;
                const size_t gi = ((size_t)batch * T_DIM + q0 + 32 * w + qr) * D_DIM + dt * 32 + cc;
                const float gv = gelu_tanh(x[gi]);
                out[gi] = gv + alpha * (gv - mu);
            }
        }
    }
}

// ---------------------------------------------------------------------------
// reduce: sum bf16 partials (plain add across segments) + epilogue
// ---------------------------------------------------------------------------
__global__ __launch_bounds__(256) void reduce_kernel(
    const float* __restrict__ x,
    const float* __restrict__ lar,
    const unsigned short* __restrict__ partO,
    const float* __restrict__ partL,
    float* __restrict__ out,
    int MS)
{
    const int idx = blockIdx.x * 256 + threadIdx.x;  // 524288 threads
    const int row = idx >> 5;
    const int d0 = (idx & 31) << 2;
    const int batch = row >> 13, q = row & 8191;
    const int tl = 63 - (q >> 7);
    const int R = 8192 - 128 * tl;
    int nseg = (R + 511) >> 9; if (nseg > MS) nseg = MS;
    if (nseg <= 1) return;                           // written directly by attn
    const int roff = q & 127;
    const int tile_lin = tl * 2 + batch;

    float o0 = 0.f, o1 = 0.f, o2 = 0.f, o3 = 0.f, L = 0.f;
    for (int s = 0; s < nseg; ++s) {
        const size_t slot = (size_t)tile_lin * MS + s;
        const unsigned short* po = partO + slot * (128 * 128) + roff * 128 + d0;
        o0 += bf2f(po[0]); o1 += bf2f(po[1]); o2 += bf2f(po[2]); o3 += bf2f(po[3]);
        L += partL[slot * 128 + roff];
    }
    const float invL = 1.0f / L;
    const float alpha = softplus_f(lar[0]);
    const size_t gi = (size_t)row * D_DIM + d0;
    const f32x4 xv = *reinterpret_cast<const f32x4*>(x + gi);
    f32x4 ov;
    const float mu[4] = {o0 * invL, o1 * invL, o2 * invL, o3 * invL};
    #pragma unroll
    for (int j = 0; j < 4; ++j) {
        const float gv = gelu_tanh(xv[j]);
        ov[j] = gv + alpha * (gv - mu[j]);
    }
    *reinterpret_cast<f32x4*>(out + gi) = ov;
}

extern "C" void kernel_launch(void* const* d_in, const int* in_sizes, int n_in,
                              void* d_out, int out_size, void* d_ws, size_t ws_size,
                              hipStream_t stream) {
    const float* x = (const float*)d_in[0];
    const float* lbr = (const float*)d_in[1];
    const float* lar = (const float*)d_in[2];
    float* out = (float*)d_out;

    unsigned short* on = (unsigned short*)d_ws;              // 4 MiB
    unsigned short* vT = on + (size_t)2 * T_DIM * D_DIM;     // 4 MiB
    const size_t fixed = (size_t)8 * 1024 * 1024;

    int MS = 1;
    if (ws_size > fixed + (1 << 20)) {
        const long long per = 128ll * (128 * 128 * 2 + 128 * 4); // partO + partL per seg level
        long long avail = (long long)ws_size - (long long)fixed - (1 << 20);
        MS = (int)(avail / per);
        if (MS > 16) MS = 16;
        if (MS < 1) MS = 1;
    }
    unsigned short* partO = (unsigned short*)((char*)d_ws + fixed);
    float* partL = (float*)((char*)partO + (size_t)128 * MS * 128 * 128 * 2);

    prep_kernel<<<dim3(512), dim3(256), 0, stream>>>(x, on, vT);
    attn_kernel<<<dim3(128, MS), dim3(256), 0, stream>>>(x, on, vT, lbr, lar,
                                                         partO, partL, out, MS);
    if (MS > 1)
        reduce_kernel<<<dim3(2048), dim3(256), 0, stream>>>(x, lar, partO, partL, out, MS);
}